// Round 3
// baseline (221.834 us; speedup 1.0000x reference)
//
#include <hip/hip_runtime.h>

// Problem: out[b, x, y] = sum_k inputs[b,k] * W[y*82+x, k] + bias[y*82+x]
//   B=8192, F=64, P=5494 (NX=82, NY=67); out flat: b*5494 + c, c = x*67+y,
//   inverse permutation p(c) = (c%67)*82 + c/67.
//
// R6: LDS-free epilogue via swapped-operand MFMA. R3 (256-B runs, 43-strip
// interleave) == R5 (1-KB time-sequential runs) == ~89 us gemm -> store
// pattern/granularity is NOT the limiter; suspect the shared structure
// (LDS transpose + barrier/lgkm serialization + low wave count). This version:
// compute mfma(W_frag, A_frag) so C/D layout (col=lane&15, row=quad*4+reg)
// maps lane->out-row, reg->4 consecutive out-cols: each lane's f32x4 acc IS a
// contiguous 16-B row slice. Epilogue = +bias (contiguous f32x4 from bp) and
// one dwordx4 store. No LDS, no barriers, no transpose. 8192 independent
// waves (2048 blocks, 4 waves/SIMD target), each owns 16 rows x 5-6
// consecutive 64-col chunks (column-sequential run extension), b-frags
// double-buffered across chunks.

typedef __bf16 bf16x8 __attribute__((ext_vector_type(8)));
typedef float f32x4 __attribute__((ext_vector_type(4)));
typedef float f32x4u __attribute__((ext_vector_type(4), aligned(4)));

#define B_DIM 8192
#define P_DIM 5494
#define PP_DIM 5504   // 86 chunks of 64 cols
#define NY_C 67

// round-to-nearest-even fp32 -> bf16
__device__ __forceinline__ unsigned short f2bf(float f) {
  unsigned int u = __float_as_uint(f);
  unsigned int r = u + 0x7fffu + ((u >> 16) & 1u);
  return (unsigned short)(r >> 16);
}

// Fused prep (identical to the verified R3 prep): blocks [0,512): convert A
// fp32->bf16 (4 elems/thread). blocks [512,856): permute+convert W rows
// (Wp[c] = W[p(c)]), build permuted zero-padded bias.
__global__ void prep_kernel(const float* __restrict__ A,
                            const float* __restrict__ W,
                            const float* __restrict__ bias,
                            unsigned short* __restrict__ Abf,
                            unsigned short* __restrict__ Wp,
                            float* __restrict__ bp) {
  if (blockIdx.x < 512) {
    int i = (blockIdx.x * 256 + threadIdx.x) * 4;
    float4 v = *(const float4*)(A + i);
    *(ushort4*)(Abf + i) = make_ushort4(f2bf(v.x), f2bf(v.y), f2bf(v.z), f2bf(v.w));
  } else {
    int t = (blockIdx.x - 512) * 256 + threadIdx.x;
    int c = t >> 4;          // Wp row (permuted pixel index), 16 threads/row
    int kq = (t & 15) * 4;   // k offset (4 floats)
    int x = c / NY_C;
    int y = c - x * NY_C;
    if (c < P_DIM) {
      int p = y * 82 + x;
      float4 v = *(const float4*)(W + p * 64 + kq);
      *(ushort4*)(Wp + c * 64 + kq) =
          make_ushort4(f2bf(v.x), f2bf(v.y), f2bf(v.z), f2bf(v.w));
      if (kq == 0) bp[c] = bias[p];
    } else {
      *(ushort4*)(Wp + c * 64 + kq) = make_ushort4(0, 0, 0, 0);
      if (kq == 0) bp[c] = 0.0f;
    }
  }
}

// GEMM: 2048 blocks x 256 thr = 8192 waves. Wave w: row group g = w>>4
// (rows g*16..g*16+15), col span s = w&15 over 86 chunks of 64 cols
// (s<6: 6 chunks from 6s; s>=6: 5 chunks from 36+5(s-6)).
__global__ __launch_bounds__(256, 4) void gemm_kernel(
    const unsigned short* __restrict__ Abf,  // [8192, 64] bf16
    const unsigned short* __restrict__ Wp,   // [5504, 64] bf16 (permuted)
    const float* __restrict__ bp,            // [5504] f32 (permuted, padded)
    float* __restrict__ out) {               // [8192, 5494] f32
  const int lane = threadIdx.x & 63;
  const int w = (blockIdx.x << 2) + (threadIdx.x >> 6);
  const int g = w >> 4;
  const int s = w & 15;
  const int quad = lane >> 4;
  const int l16 = lane & 15;
  const int m0 = g * 16;
  const int nchunks = (s < 6) ? 6 : 5;
  const int c0 = (s < 6) ? 6 * s : 36 + 5 * (s - 6);

  // A fragments (used as the MFMA *B*-operand): lane holds
  // Abf[m0 + l16][k = quad*8 + j], j=0..7.
  const unsigned short* ar = Abf + (size_t)(m0 + l16) * 64 + quad * 8;
  const bf16x8 a0 = *(const bf16x8*)(ar);
  const bf16x8 a1 = *(const bf16x8*)(ar + 32);

  // Per-lane output row base (row fixed for the whole wave lifetime).
  float* const rowp = out + (size_t)(m0 + l16) * P_DIM;

  bf16x8 bA[4][2], bB[4][2];

  auto loadB = [&](int c, bf16x8 (&bf)[4][2]) {
    const unsigned short* wr = Wp + (size_t)(c * 64 + l16) * 64 + quad * 8;
#pragma unroll
    for (int ni = 0; ni < 4; ++ni) {
      bf[ni][0] = *(const bf16x8*)(wr + ni * 1024);        // +16 rows * 64
      bf[ni][1] = *(const bf16x8*)(wr + ni * 1024 + 32);
    }
  };

  // Swapped-operand MFMA: D = Wp_tile . Abf_tile^T. C/D layout col=lane&15,
  // row=quad*4+reg  =>  lane l16 = out row (m0+l16), reg r = out col
  // nb + ni*16 + quad*4 + r. Each lane's f32x4 = 16 B contiguous of one row.
  auto cs = [&](int c, bf16x8 (&bf)[4][2]) {
    const int nb = c * 64;
    const bool tail = (c == 85);
#pragma unroll
    for (int ni = 0; ni < 4; ++ni) {
      f32x4 acc = {0.0f, 0.0f, 0.0f, 0.0f};
      acc = __builtin_amdgcn_mfma_f32_16x16x32_bf16(bf[ni][0], a0, acc, 0, 0, 0);
      acc = __builtin_amdgcn_mfma_f32_16x16x32_bf16(bf[ni][1], a1, acc, 0, 0, 0);
      const int gcol = nb + ni * 16 + quad * 4;
      acc += *(const f32x4*)(bp + gcol);   // bias, contiguous 16 B
      float* p = rowp + gcol;
      if (!tail) {
        *(f32x4u*)p = acc;
      } else {
#pragma unroll
        for (int e = 0; e < 4; ++e)
          if (gcol + e < P_DIM) p[e] = acc[e];
      }
    }
  };

  loadB(c0, bA);
  int i = 0;
  for (;;) {
    if (i + 1 < nchunks) loadB(c0 + i + 1, bB);
    cs(c0 + i, bA);
    if (++i == nchunks) break;
    if (i + 1 < nchunks) loadB(c0 + i + 1, bA);
    cs(c0 + i, bB);
    if (++i == nchunks) break;
  }
}

extern "C" void kernel_launch(void* const* d_in, const int* in_sizes, int n_in,
                              void* d_out, int out_size, void* d_ws, size_t ws_size,
                              hipStream_t stream) {
  (void)in_sizes; (void)n_in; (void)out_size; (void)ws_size;
  const float* A = (const float*)d_in[0];      // [8192, 64]
  const float* W = (const float*)d_in[1];      // [5494, 64]
  const float* bias = (const float*)d_in[2];   // [5494]
  float* out = (float*)d_out;                  // [8192, 82, 67, 1] contiguous

  // workspace layout (~1.8 MB)
  unsigned short* Abf = (unsigned short*)d_ws;                       // 1 MB
  unsigned short* Wp = (unsigned short*)((char*)d_ws + 1048576);     // 704512 B
  float* bp = (float*)((char*)d_ws + 1048576 + 704512);              // 22016 B

  prep_kernel<<<856, 256, 0, stream>>>(A, W, bias, Abf, Wp, bp);
  gemm_kernel<<<2048, 256, 0, stream>>>(Abf, Wp, bp, out);
}